// Round 10
// baseline (997.465 us; speedup 1.0000x reference)
//
#include <hip/hip_runtime.h>
#include <math.h>

#define B_ 32
#define T_ 256
#define H_ 128
#define KL_ 500
#define KS_ 10

typedef _Float16 h8 __attribute__((ext_vector_type(8)));  // 16B = 8 fp16
typedef _Float16 h2 __attribute__((ext_vector_type(2)));

// ---------------- K1: convs (+ fused hb) ----------------
__global__ void k_front(const float* __restrict__ in1, const float* __restrict__ in2,
                        const float* __restrict__ wl, const float* __restrict__ bl,
                        const float* __restrict__ ws, const float* __restrict__ bs,
                        const float* __restrict__ h, const float* __restrict__ Whh,
                        const float* __restrict__ bh,
                        float* __restrict__ xf, float* __restrict__ hb,
                        float* __restrict__ dout) {
    int b = blockIdx.x, oc = blockIdx.y;
    int t = threadIdx.x;  // 256 threads
    if (oc == 6) {
        __shared__ float hrow[128];
        if (t < 128) hrow[t] = h[b * 128 + t];
        __syncthreads();
        if (t < 128) {
            float acc = bh[t];
            #pragma unroll 4
            for (int k = 0; k < 128; ++k) acc += hrow[k] * Whh[t * 128 + k];
            hb[b * 128 + t] = acc;
            dout[32 + b * 128 + t] = hrow[t];
        }
        return;
    }
    __shared__ float s_in[755 * 3];
    __shared__ float s_w[3 * KL_];
    if (oc < 3) {
        int o = oc;
        for (int i = t; i < 755 * 3; i += 256) s_in[i] = in1[b * 755 * 3 + i];
        for (int i = t; i < 3 * KL_; i += 256) s_w[i] = wl[o * 3 * KL_ + i];
        __syncthreads();
        float acc = bl[o];
        for (int i = 0; i < 3; ++i) {
            const float* wrow = &s_w[i * KL_];
            #pragma unroll 4
            for (int k = 0; k < KL_; ++k)
                acc += s_in[(t + k) * 3 + i] * wrow[k];
        }
        xf[(b * T_ + t) * 6 + o] = acc;
    } else {
        int o = oc - 3;
        for (int i = t; i < 265 * 3; i += 256) s_in[i] = in2[b * 265 * 3 + i];
        for (int i = t; i < 3 * KS_; i += 256) s_w[i] = ws[o * 3 * KS_ + i];
        __syncthreads();
        float acc = bs[o];
        for (int i = 0; i < 3; ++i) {
            #pragma unroll
            for (int k = 0; k < KS_; ++k)
                acc += s_in[(t + k) * 3 + i] * s_w[i * KS_ + k];
        }
        xf[(b * T_ + t) * 6 + 3 + o] = acc;
    }
}

// ---------------- K2: features -> lane-permuted fp16 tiles ----------------
__global__ void k_feat(const float* __restrict__ xf, const float* __restrict__ in3,
                       const float* __restrict__ hb, const float* __restrict__ Wih,
                       const float* __restrict__ tk, const float* __restrict__ tv,
                       const float* __restrict__ tq,
                       _Float16* __restrict__ rwP, _Float16* __restrict__ clP,
                       float* __restrict__ lblT, float* __restrict__ outq) {
    int t = blockIdx.x;
    int tid = threadIdx.x;
    __shared__ float out_s[B_ * H_];
    __shared__ __align__(16) float tkc[16 * H_];
    __shared__ __align__(16) float tvc[16 * H_];
    __shared__ __align__(16) float tqc[16 * H_];

    for (int o = 0; o < 16; ++o) {
        int idx = o * 256 + tid;
        int b = idx >> 7, hh = idx & 127;
        const float* w = &Wih[hh * 9];
        const float* x6 = &xf[(b * T_ + t) * 6];
        const float* x3 = &in3[(b * T_ + t) * 3];
        float acc = hb[idx];
        acc += x6[0] * w[0] + x6[1] * w[1] + x6[2] * w[2]
             + x6[3] * w[3] + x6[4] * w[4] + x6[5] * w[5]
             + x3[0] * w[6] + x3[1] * w[7] + x3[2] * w[8];
        out_s[idx] = acc;
    }
    __syncthreads();

    float a_tr[16], a_lb[16], a_tq[16];
    #pragma unroll
    for (int o = 0; o < 16; ++o) { a_tr[o] = 0.f; a_lb[o] = 0.f; a_tq[o] = 0.f; }
    const bool last = (t == T_ - 1);

    for (int kc = 0; kc < 8; ++kc) {
        __syncthreads();
        {
            const float4* s1 = (const float4*)(tk + kc * 2048);
            const float4* s2 = (const float4*)(tv + kc * 2048);
            float4* d1 = (float4*)tkc;
            float4* d2 = (float4*)tvc;
            d1[tid * 2]     = s1[tid * 2];
            d1[tid * 2 + 1] = s1[tid * 2 + 1];
            d2[tid * 2]     = s2[tid * 2];
            d2[tid * 2 + 1] = s2[tid * 2 + 1];
            if (last) {
                const float4* s3 = (const float4*)(tq + kc * 2048);
                float4* d3 = (float4*)tqc;
                d3[tid * 2]     = s3[tid * 2];
                d3[tid * 2 + 1] = s3[tid * 2 + 1];
            }
        }
        __syncthreads();
        for (int o = 0; o < 16; ++o) {
            int idx = o * 256 + tid;
            int b = idx >> 7, hh = idx & 127;
            const float* os = &out_s[b * 128 + kc * 16];
            #pragma unroll
            for (int k2 = 0; k2 < 16; ++k2) {
                float ov = os[k2];
                a_tr[o] += ov * tkc[k2 * 128 + hh];
                a_lb[o] += ov * tvc[k2 * 128 + hh];
                if (last) a_tq[o] += ov * tqc[k2 * 128 + hh];
            }
        }
    }
    for (int o = 0; o < 16; ++o) {
        int idx = o * 256 + tid;
        int b = idx >> 7, hh = idx & 127;  // value = trv[t][b][hh]
        _Float16 v16 = (_Float16)a_tr[o];
        int p = hh & 63;
        rwP[t * 4096 + ((p >> 3) << 9) + ((2 * b + (hh >> 6)) << 3) + (p & 7)] = v16;
        int q = ((hh & 1) << 5) + b;
        clP[t * 4096 + ((q >> 3) << 9) + ((hh >> 1) << 3) + (q & 7)] = v16;
        lblT[t * 4096 + hh * 32 + b] = a_lb[o];
        if (last) outq[idx] = a_tq[o];
    }
}

// ---------------- shared step building blocks ----------------
#define DPP_ADD(S, CTRL)                                                           \
  do { int _d = __builtin_amdgcn_update_dpp(0, __float_as_int(S), (CTRL), 0xF,     \
                                            0xF, true);                            \
       (S) += __int_as_float(_d); } while (0)

#define PHASEA_J(j, RW)                                                            \
  { h8 xv = RW[j]; float4 wa = wreg[2 * (j)], wb = wreg[2 * (j) + 1];              \
    a0 = fmaf((float)xv[0], wa.x, a0); a1 = fmaf((float)xv[1], wa.y, a1);          \
    a2 = fmaf((float)xv[2], wa.z, a2); a3 = fmaf((float)xv[3], wa.w, a3);          \
    a4 = fmaf((float)xv[4], wb.x, a4); a5 = fmaf((float)xv[5], wb.y, a5);          \
    a6 = fmaf((float)xv[6], wb.z, a6); a7 = fmaf((float)xv[7], wb.w, a7); }

#if __has_builtin(__builtin_amdgcn_fdot2)
#define FDOT2(ci, gi, acc)                                                         \
  __builtin_amdgcn_fdot2(__builtin_bit_cast(h2, (ci)),                             \
                         __builtin_bit_cast(h2, (gi)), (acc), false)
#else
static __device__ __forceinline__ float fdot2_sw(int a, int b, float c) {
    h2 ha = __builtin_bit_cast(h2, a), hb2 = __builtin_bit_cast(h2, b);
    return fmaf((float)ha.y, (float)hb2.y, fmaf((float)ha.x, (float)hb2.x, c));
}
#define FDOT2(ci, gi, acc) fdot2_sw((ci), (gi), (acc))
#endif

// ---------------- K3: Adam scan — dot2 phase B, 16 packed readlanes ----------------
#define SCAN_STEP(RW, CL, LB, TT)                                                  \
  do {                                                                             \
    pb1 *= BB1; pb2 *= BB2;                                                        \
    const float na = (-lr) * __builtin_amdgcn_sqrtf(1.0f - pb2) *                  \
                     __builtin_amdgcn_rcpf(1.0f - pb1);                            \
    const float bml = bm - (LB);                                                   \
    float a0 = 0.f, a1 = 0.f, a2 = 0.f, a3 = 0.f;                                  \
    float a4 = 0.f, a5 = 0.f, a6 = 0.f, a7 = 0.f;                                  \
    PHASEA_J(0, RW) PHASEA_J(1, RW) PHASEA_J(2, RW) PHASEA_J(3, RW)                \
    PHASEA_J(4, RW) PHASEA_J(5, RW) PHASEA_J(6, RW) PHASEA_J(7, RW)                \
    float pp = ((a0 + a2) + (a1 + a3)) + ((a4 + a6) + (a5 + a7));                  \
    int po = __builtin_amdgcn_update_dpp(0, __float_as_int(pp), 0xB1, 0xF, 0xF,    \
                                         true);                                    \
    float pred = pp + __int_as_float(po);                                          \
    float gh = pred + bml;   /* unscaled grad: cg folded later */                  \
    /* prefetch rows + lbl for TT+2 */                                             \
    {                                                                              \
      const int tpre = ((TT) + 2 < 256) ? ((TT) + 2) : 255;                        \
      const h8* rs = (const h8*)(rwP + (size_t)tpre * 4096);                       \
      _Pragma("unroll")                                                            \
      for (int j = 0; j < 8; ++j) RW[j] = rs[j * 64 + lane];                       \
      LB = lblT[(size_t)tpre * 4096 + lblidx];                                     \
    }                                                                              \
    /* pack (gh[2i], gh[2i+1]) on lanes 4i: neighbor row via quad_perm[2,3,0,1] */ \
    int gnb = __builtin_amdgcn_update_dpp(0, __float_as_int(gh), 0x4E, 0xF, 0xF,   \
                                          true);                                   \
    int pkg = __builtin_bit_cast(int,                                              \
        __builtin_amdgcn_cvt_pkrtz(gh, __int_as_float(gnb)));                      \
    /* bias grad: butterfly (exact sum over 32 rows, pair-replicated lanes) */     \
    float gsum = gh;                                                               \
    DPP_ADD(gsum, 0x4E); DPP_ADD(gsum, 0x124); DPP_ADD(gsum, 0x128);               \
    gsum += __shfl_xor(gsum, 16); gsum += __shfl_xor(gsum, 32);                    \
    /* 16 packed readlanes */                                                      \
    int gp[16];                                                                    \
    _Pragma("unroll")                                                              \
    for (int i = 0; i < 16; ++i)                                                   \
      gp[i] = __builtin_amdgcn_readlane(pkg, 4 * i);                               \
    /* phase B: 32 dot2 (2 MACs each, fp32 accum) */                               \
    float f0 = 0.f, f1 = 0.f, f2 = 0.f, f3 = 0.f;                                  \
    float f4 = 0.f, f5 = 0.f, f6 = 0.f, f7 = 0.f;                                  \
    _Pragma("unroll")                                                              \
    for (int j = 0; j < 4; ++j) {                                                  \
      int4 cj = __builtin_bit_cast(int4, CL[j]);                                   \
      f0 = FDOT2(cj.x, gp[4 * j + 0], f0);                                         \
      f1 = FDOT2(cj.y, gp[4 * j + 1], f1);                                         \
      f2 = FDOT2(cj.z, gp[4 * j + 2], f2);                                         \
      f3 = FDOT2(cj.w, gp[4 * j + 3], f3);                                         \
    }                                                                              \
    _Pragma("unroll")                                                              \
    for (int j = 0; j < 4; ++j) {                                                  \
      int4 cj = __builtin_bit_cast(int4, CL[j + 4]);                               \
      f4 = FDOT2(cj.x, gp[4 * j + 0], f4);                                         \
      f5 = FDOT2(cj.y, gp[4 * j + 1], f5);                                         \
      f6 = FDOT2(cj.z, gp[4 * j + 2], f6);                                         \
      f7 = FDOT2(cj.w, gp[4 * j + 3], f7);                                         \
    }                                                                              \
    const float gk0 = cg * ((f0 + f2) + (f1 + f3));                                \
    const float gk1 = cg * ((f4 + f6) + (f5 + f7));                                \
    /* prefetch cols for TT+2 */                                                   \
    {                                                                              \
      const int tpre = ((TT) + 2 < 256) ? ((TT) + 2) : 255;                        \
      const h8* cs = (const h8*)(clP + (size_t)tpre * 4096);                       \
      _Pragma("unroll")                                                            \
      for (int j = 0; j < 8; ++j) CL[j] = cs[j * 64 + lane];                       \
    }                                                                              \
    /* Adam W */                                                                   \
    {                                                                              \
      float t0 = OB1 * gk0; mW0 = fmaf(BB1, mW0, t0);                              \
      float t1 = gk0 * gk0; float t2 = OB2 * t1; vW0 = fmaf(BB2, vW0, t2);         \
      float r0 = __builtin_amdgcn_rsqf(vW0 + SEPS);                                \
      w0 = fmaf(mW0 * r0, na, w0);                                                 \
      float t3 = OB1 * gk1; mW1 = fmaf(BB1, mW1, t3);                              \
      float t4 = gk1 * gk1; float t5 = OB2 * t4; vW1 = fmaf(BB2, vW1, t5);         \
      float r1 = __builtin_amdgcn_rsqf(vW1 + SEPS);                                \
      w1 = fmaf(mW1 * r1, na, w1);                                                 \
    }                                                                              \
    *(float2*)&w_s[2 * lane] = make_float2(w0, w1);                                \
    _Pragma("unroll")                                                              \
    for (int j = 0; j < 16; ++j) wreg[j] = *(const float4*)&w_s[hf64 + 4 * j];     \
    /* bias Adam */                                                                \
    {                                                                              \
      const float gb = cg * gsum;                                                  \
      float t6 = OB1 * gb; mb = fmaf(BB1, mb, t6);                                 \
      float t7 = gb * gb; float t8 = OB2 * t7; vb = fmaf(BB2, vb, t8);             \
      float rb = __builtin_amdgcn_rsqf(vb + SEPS);                                 \
      bm = fmaf(mb * rb, na, bm);                                                  \
    }                                                                              \
  } while (0)

__global__
__attribute__((amdgpu_flat_work_group_size(64, 64), amdgpu_waves_per_eu(1, 1)))
void k_scan(
    const _Float16* __restrict__ rwP, const _Float16* __restrict__ clP,
    const float* __restrict__ lblT,
    const float* __restrict__ Wm0, const float* __restrict__ bm0,
    const float* __restrict__ outq, float* __restrict__ hi_ws) {
    const int h = blockIdx.x;
    const int lane = threadIdx.x;
    const int row = lane >> 1;
    const int hf = lane & 1;
    const int hf64 = hf * 64;
    const int rowbase = row * 128 + hf64;
    const int lblidx = h * 32 + row;

    __shared__ __align__(16) float w_s[H_];

    float2 wv = *(const float2*)&Wm0[h * 128 + 2 * lane];
    float w0 = wv.x, w1 = wv.y;
    float mW0 = 0.f, vW0 = 0.f, mW1 = 0.f, vW1 = 0.f;
    float bm = bm0[h];
    float mb = 0.f, vb = 0.f, pb1 = 1.f, pb2 = 1.f;

    *(float2*)&w_s[2 * lane] = wv;

    float4 wreg[16];
    #pragma unroll
    for (int j = 0; j < 16; ++j) wreg[j] = *(const float4*)&w_s[hf64 + 4 * j];

    h8 rwA[8], rwB[8], clA[8], clB[8];
    float lA, lB;
    {
        const h8* r0 = (const h8*)(rwP);
        const h8* c0 = (const h8*)(clP);
        const h8* r1 = (const h8*)(rwP + 4096);
        const h8* c1 = (const h8*)(clP + 4096);
        #pragma unroll
        for (int j = 0; j < 8; ++j) rwA[j] = r0[j * 64 + lane];
        #pragma unroll
        for (int j = 0; j < 8; ++j) clA[j] = c0[j * 64 + lane];
        lA = lblT[lblidx];
        #pragma unroll
        for (int j = 0; j < 8; ++j) rwB[j] = r1[j * 64 + lane];
        #pragma unroll
        for (int j = 0; j < 8; ++j) clB[j] = c1[j * 64 + lane];
        lB = lblT[4096 + lblidx];
    }

    const float cg = 2.0f / 4096.0f;
    const float lr = 0.01f, BB1 = 0.9f, BB2 = 0.999f;
    const float OB1 = 0.1f, OB2 = 0.001f;
    const float SEPS = 1e-16f;

    for (int t = 0; t < T_; t += 2) {
        SCAN_STEP(rwA, clA, lA, t);
        SCAN_STEP(rwB, clB, lB, t + 1);
    }

    // epilogue: hi[:,h] = outq @ Wm_final[h,:] + bm_final (fp32 w in wreg)
    {
        const float4* es = (const float4*)(outq + rowbase);
        float ax = 0.f, ay = 0.f, az = 0.f, aw = 0.f;
        #pragma unroll
        for (int j = 0; j < 16; ++j) {
            float4 xv = es[j];
            float4 wv4 = wreg[j];
            ax = fmaf(xv.x, wv4.x, ax); ay = fmaf(xv.y, wv4.y, ay);
            az = fmaf(xv.z, wv4.z, az); aw = fmaf(xv.w, wv4.w, aw);
        }
        float pp = (ax + az) + (ay + aw);
        int po = __builtin_amdgcn_update_dpp(0, __float_as_int(pp), 0xB1, 0xF, 0xF, true);
        float pred = pp + __int_as_float(po);
        if (hf == 0) hi_ws[row * 128 + h] = pred + bm;
    }
}

// ---------------- K3b: DIAGNOSTIC probe — round-8 body minus per-step VMEM ----------------
// 4x256 = 1024 steps, tiles loaded once. Measures the compute+LDS+readlane core.
#define PROBE_STEP(RW, CL, LB)                                                     \
  do {                                                                             \
    pb1 *= BB1; pb2 *= BB2;                                                        \
    const float na = (-lr) * __builtin_amdgcn_sqrtf(1.0f - pb2) *                  \
                     __builtin_amdgcn_rcpf(1.0f - pb1);                            \
    const float cgbml = cg * (bm - (LB));                                          \
    float a0 = 0.f, a1 = 0.f, a2 = 0.f, a3 = 0.f;                                  \
    float a4 = 0.f, a5 = 0.f, a6 = 0.f, a7 = 0.f;                                  \
    PHASEA_J(0, RW) PHASEA_J(1, RW) PHASEA_J(2, RW) PHASEA_J(3, RW)                \
    PHASEA_J(4, RW) PHASEA_J(5, RW) PHASEA_J(6, RW) PHASEA_J(7, RW)                \
    float pp = ((a0 + a2) + (a1 + a3)) + ((a4 + a6) + (a5 + a7));                  \
    int po = __builtin_amdgcn_update_dpp(0, __float_as_int(pp), 0xB1, 0xF, 0xF,    \
                                         true);                                    \
    float pred = pp + __int_as_float(po);                                          \
    float g = fmaf(cg, pred, cgbml);                                               \
    float gsum = g;                                                                \
    DPP_ADD(gsum, 0x4E); DPP_ADD(gsum, 0x124); DPP_ADD(gsum, 0x128);               \
    gsum += __shfl_xor(gsum, 16); gsum += __shfl_xor(gsum, 32);                    \
    float ga[32];                                                                  \
    _Pragma("unroll")                                                              \
    for (int b = 0; b < 32; ++b)                                                   \
      ga[b] = __int_as_float(                                                      \
          __builtin_amdgcn_readlane(__float_as_int(g), 2 * b));                    \
    float f0 = 0.f, f1 = 0.f, f2 = 0.f, f3 = 0.f;                                  \
    float f4 = 0.f, f5 = 0.f, f6 = 0.f, f7 = 0.f;                                  \
    _Pragma("unroll")                                                              \
    for (int j = 0; j < 4; ++j) {                                                  \
      h8 cv = CL[j];                                                               \
      f0 = fmaf(ga[8 * j + 0], (float)cv[0], f0);                                  \
      f1 = fmaf(ga[8 * j + 1], (float)cv[1], f1);                                  \
      f2 = fmaf(ga[8 * j + 2], (float)cv[2], f2);                                  \
      f3 = fmaf(ga[8 * j + 3], (float)cv[3], f3);                                  \
      f0 = fmaf(ga[8 * j + 4], (float)cv[4], f0);                                  \
      f1 = fmaf(ga[8 * j + 5], (float)cv[5], f1);                                  \
      f2 = fmaf(ga[8 * j + 6], (float)cv[6], f2);                                  \
      f3 = fmaf(ga[8 * j + 7], (float)cv[7], f3);                                  \
    }                                                                              \
    _Pragma("unroll")                                                              \
    for (int j = 0; j < 4; ++j) {                                                  \
      h8 cv = CL[j + 4];                                                           \
      f4 = fmaf(ga[8 * j + 0], (float)cv[0], f4);                                  \
      f5 = fmaf(ga[8 * j + 1], (float)cv[1], f5);                                  \
      f6 = fmaf(ga[8 * j + 2], (float)cv[2], f6);                                  \
      f7 = fmaf(ga[8 * j + 3], (float)cv[3], f7);                                  \
      f4 = fmaf(ga[8 * j + 4], (float)cv[4], f4);                                  \
      f5 = fmaf(ga[8 * j + 5], (float)cv[5], f5);                                  \
      f6 = fmaf(ga[8 * j + 6], (float)cv[6], f6);                                  \
      f7 = fmaf(ga[8 * j + 7], (float)cv[7], f7);                                  \
    }                                                                              \
    const float gk0 = (f0 + f2) + (f1 + f3);                                       \
    const float gk1 = (f4 + f6) + (f5 + f7);                                       \
    {                                                                              \
      float t0 = OB1 * gk0; mW0 = fmaf(BB1, mW0, t0);                              \
      float t1 = gk0 * gk0; float t2 = OB2 * t1; vW0 = fmaf(BB2, vW0, t2);         \
      float r0 = __builtin_amdgcn_rsqf(vW0 + SEPS);                                \
      w0 = fmaf(mW0 * r0, na, w0);                                                 \
      float t3 = OB1 * gk1; mW1 = fmaf(BB1, mW1, t3);                              \
      float t4 = gk1 * gk1; float t5 = OB2 * t4; vW1 = fmaf(BB2, vW1, t5);         \
      float r1 = __builtin_amdgcn_rsqf(vW1 + SEPS);                                \
      w1 = fmaf(mW1 * r1, na, w1);                                                 \
    }                                                                              \
    *(float2*)&w_s[2 * lane] = make_float2(w0, w1);                                \
    _Pragma("unroll")                                                              \
    for (int j = 0; j < 16; ++j) wreg[j] = *(const float4*)&w_s[hf64 + 4 * j];     \
    {                                                                              \
      float t6 = OB1 * gsum; mb = fmaf(BB1, mb, t6);                               \
      float t7 = gsum * gsum; float t8 = OB2 * t7; vb = fmaf(BB2, vb, t8);         \
      float rb = __builtin_amdgcn_rsqf(vb + SEPS);                                 \
      bm = fmaf(mb * rb, na, bm);                                                  \
    }                                                                              \
  } while (0)

__global__
__attribute__((amdgpu_flat_work_group_size(64, 64), amdgpu_waves_per_eu(1, 1)))
void k_probe(
    const _Float16* __restrict__ rwP, const _Float16* __restrict__ clP,
    const float* __restrict__ lblT,
    const float* __restrict__ Wm0, const float* __restrict__ bm0,
    float* __restrict__ pws) {
    const int h = blockIdx.x;
    const int lane = threadIdx.x;
    const int row = lane >> 1;
    const int hf = lane & 1;
    const int hf64 = hf * 64;
    const int lblidx = h * 32 + row;

    __shared__ __align__(16) float w_s[H_];

    float2 wv = *(const float2*)&Wm0[h * 128 + 2 * lane];
    float w0 = wv.x, w1 = wv.y;
    float mW0 = 0.f, vW0 = 0.f, mW1 = 0.f, vW1 = 0.f;
    float bm = bm0[h];
    float mb = 0.f, vb = 0.f, pb1 = 1.f, pb2 = 1.f;

    *(float2*)&w_s[2 * lane] = wv;

    float4 wreg[16];
    #pragma unroll
    for (int j = 0; j < 16; ++j) wreg[j] = *(const float4*)&w_s[hf64 + 4 * j];

    h8 rwA[8], rwB[8], clA[8], clB[8];
    float lA, lB;
    {
        const h8* r0 = (const h8*)(rwP);
        const h8* c0 = (const h8*)(clP);
        const h8* r1 = (const h8*)(rwP + 4096);
        const h8* c1 = (const h8*)(clP + 4096);
        #pragma unroll
        for (int j = 0; j < 8; ++j) rwA[j] = r0[j * 64 + lane];
        #pragma unroll
        for (int j = 0; j < 8; ++j) clA[j] = c0[j * 64 + lane];
        lA = lblT[lblidx];
        #pragma unroll
        for (int j = 0; j < 8; ++j) rwB[j] = r1[j * 64 + lane];
        #pragma unroll
        for (int j = 0; j < 8; ++j) clB[j] = c1[j * 64 + lane];
        lB = lblT[4096 + lblidx];
    }

    const float cg = 2.0f / 4096.0f;
    const float lr = 0.01f, BB1 = 0.9f, BB2 = 0.999f;
    const float OB1 = 0.1f, OB2 = 0.001f;
    const float SEPS = 1e-16f;

    for (int r = 0; r < 4; ++r) {
        for (int t = 0; t < T_; t += 2) {
            PROBE_STEP(rwA, clA, lA);
            PROBE_STEP(rwB, clB, lB);
        }
    }
    // keep every chain live (w0/w1 <- phases+Adam, bm <- bias, wreg <- LDS roundtrip)
    pws[h * 64 + lane] = w0 + 0.5f * w1 + 0.25f * bm + 1e-6f * wreg[3].y;
}

// ---------------- K4: y = hi@W_ho.T + b_o ; out = y@out_W.T + out_b ----------------
__global__ void k_out(const float* __restrict__ hi, const float* __restrict__ Who,
                      const float* __restrict__ bo, const float* __restrict__ outW,
                      const float* __restrict__ outb, float* __restrict__ dout) {
    int b = blockIdx.x, hh = threadIdx.x;
    __shared__ float hrow[128];
    __shared__ float part[2];
    hrow[hh] = hi[b * 128 + hh];
    __syncthreads();
    float acc = bo[hh];
    #pragma unroll 4
    for (int k = 0; k < 128; ++k) acc += hrow[k] * Who[hh * 128 + k];
    float v = acc * outW[hh];
    v += __shfl_down(v, 32, 64);
    v += __shfl_down(v, 16, 64);
    v += __shfl_down(v, 8, 64);
    v += __shfl_down(v, 4, 64);
    v += __shfl_down(v, 2, 64);
    v += __shfl_down(v, 1, 64);
    if ((hh & 63) == 0) part[hh >> 6] = v;
    __syncthreads();
    if (hh == 0) dout[b] = part[0] + part[1] + outb[0];
}

extern "C" void kernel_launch(void* const* d_in, const int* in_sizes, int n_in,
                              void* d_out, int out_size, void* d_ws, size_t ws_size,
                              hipStream_t stream) {
    (void)in_sizes; (void)n_in; (void)out_size; (void)ws_size;
    const float* in1   = (const float*)d_in[0];
    const float* in2   = (const float*)d_in[1];
    const float* in3   = (const float*)d_in[2];
    const float* h     = (const float*)d_in[3];
    const float* Wih   = (const float*)d_in[4];
    const float* Whh   = (const float*)d_in[5];
    const float* bh    = (const float*)d_in[6];
    const float* Who   = (const float*)d_in[7];
    const float* bo    = (const float*)d_in[8];
    const float* wl    = (const float*)d_in[9];
    const float* bl    = (const float*)d_in[10];
    const float* wsc   = (const float*)d_in[11];
    const float* bsc   = (const float*)d_in[12];
    const float* tk    = (const float*)d_in[13];
    const float* tv    = (const float*)d_in[14];
    const float* tq    = (const float*)d_in[15];
    const float* Wm0   = (const float*)d_in[16];
    const float* bm0   = (const float*)d_in[17];
    const float* outW  = (const float*)d_in[18];
    const float* outb  = (const float*)d_in[19];
    float* out = (float*)d_out;

    float* wsf = (float*)d_ws;
    float*    xf    = wsf;                               // 49152 f
    float*    hb    = wsf + 49152;                       // 4096 f
    _Float16* rwH   = (_Float16*)(wsf + 53248);          // 1048576 halfs
    _Float16* clH   = (_Float16*)(wsf + 53248 + 524288); // 1048576 halfs
    float*    lblT  = wsf + 53248 + 1048576;             // 1048576 f
    float*    outq  = wsf + 53248 + 2097152;             // 4096 f
    float*    hi_ws = wsf + 53248 + 2101248;             // 4096 f
    float*    pws   = wsf + 53248 + 2105344;             // 8192 f (probe scratch)

    k_front<<<dim3(32, 7), 256, 0, stream>>>(in1, in2, wl, bl, wsc, bsc,
                                             h, Whh, bh, xf, hb, out);
    k_feat<<<256, 256, 0, stream>>>(xf, in3, hb, Wih, tk, tv, tq,
                                    rwH, clH, lblT, outq);
    k_scan<<<128, 64, 0, stream>>>(rwH, clH, lblT, Wm0, bm0, outq, hi_ws);
    k_probe<<<128, 64, 0, stream>>>(rwH, clH, lblT, Wm0, bm0, pws);
    k_out<<<32, 128, 0, stream>>>(hi_ws, Who, bo, outW, outb, out);
}

// Round 11
// 352.200 us; speedup vs baseline: 2.8321x; 2.8321x over previous
//
#include <hip/hip_runtime.h>
#include <math.h>

#define B_ 32
#define T_ 256
#define H_ 128
#define KL_ 500
#define KS_ 10

typedef _Float16 h8 __attribute__((ext_vector_type(8)));  // 16B = 8 fp16
typedef _Float16 h2 __attribute__((ext_vector_type(2)));

// ---------------- K1: convs (+ fused hb) ----------------
__global__ void k_front(const float* __restrict__ in1, const float* __restrict__ in2,
                        const float* __restrict__ wl, const float* __restrict__ bl,
                        const float* __restrict__ ws, const float* __restrict__ bs,
                        const float* __restrict__ h, const float* __restrict__ Whh,
                        const float* __restrict__ bh,
                        float* __restrict__ xf, float* __restrict__ hb,
                        float* __restrict__ dout) {
    int b = blockIdx.x, oc = blockIdx.y;
    int t = threadIdx.x;  // 256 threads
    if (oc == 6) {
        __shared__ float hrow[128];
        if (t < 128) hrow[t] = h[b * 128 + t];
        __syncthreads();
        if (t < 128) {
            float acc = bh[t];
            #pragma unroll 4
            for (int k = 0; k < 128; ++k) acc += hrow[k] * Whh[t * 128 + k];
            hb[b * 128 + t] = acc;
            dout[32 + b * 128 + t] = hrow[t];
        }
        return;
    }
    __shared__ float s_in[755 * 3];
    __shared__ float s_w[3 * KL_];
    if (oc < 3) {
        int o = oc;
        for (int i = t; i < 755 * 3; i += 256) s_in[i] = in1[b * 755 * 3 + i];
        for (int i = t; i < 3 * KL_; i += 256) s_w[i] = wl[o * 3 * KL_ + i];
        __syncthreads();
        float acc = bl[o];
        for (int i = 0; i < 3; ++i) {
            const float* wrow = &s_w[i * KL_];
            #pragma unroll 4
            for (int k = 0; k < KL_; ++k)
                acc += s_in[(t + k) * 3 + i] * wrow[k];
        }
        xf[(b * T_ + t) * 6 + o] = acc;
    } else {
        int o = oc - 3;
        for (int i = t; i < 265 * 3; i += 256) s_in[i] = in2[b * 265 * 3 + i];
        for (int i = t; i < 3 * KS_; i += 256) s_w[i] = ws[o * 3 * KS_ + i];
        __syncthreads();
        float acc = bs[o];
        for (int i = 0; i < 3; ++i) {
            #pragma unroll
            for (int k = 0; k < KS_; ++k)
                acc += s_in[(t + k) * 3 + i] * s_w[i * KS_ + k];
        }
        xf[(b * T_ + t) * 6 + 3 + o] = acc;
    }
}

// ---------------- K2: features -> lane-permuted fp16 tiles ----------------
__global__ void k_feat(const float* __restrict__ xf, const float* __restrict__ in3,
                       const float* __restrict__ hb, const float* __restrict__ Wih,
                       const float* __restrict__ tk, const float* __restrict__ tv,
                       const float* __restrict__ tq,
                       _Float16* __restrict__ rwP, _Float16* __restrict__ clP,
                       float* __restrict__ lblT, float* __restrict__ outq) {
    int t = blockIdx.x;
    int tid = threadIdx.x;
    __shared__ float out_s[B_ * H_];
    __shared__ __align__(16) float tkc[16 * H_];
    __shared__ __align__(16) float tvc[16 * H_];
    __shared__ __align__(16) float tqc[16 * H_];

    for (int o = 0; o < 16; ++o) {
        int idx = o * 256 + tid;
        int b = idx >> 7, hh = idx & 127;
        const float* w = &Wih[hh * 9];
        const float* x6 = &xf[(b * T_ + t) * 6];
        const float* x3 = &in3[(b * T_ + t) * 3];
        float acc = hb[idx];
        acc += x6[0] * w[0] + x6[1] * w[1] + x6[2] * w[2]
             + x6[3] * w[3] + x6[4] * w[4] + x6[5] * w[5]
             + x3[0] * w[6] + x3[1] * w[7] + x3[2] * w[8];
        out_s[idx] = acc;
    }
    __syncthreads();

    float a_tr[16], a_lb[16], a_tq[16];
    #pragma unroll
    for (int o = 0; o < 16; ++o) { a_tr[o] = 0.f; a_lb[o] = 0.f; a_tq[o] = 0.f; }
    const bool last = (t == T_ - 1);

    for (int kc = 0; kc < 8; ++kc) {
        __syncthreads();
        {
            const float4* s1 = (const float4*)(tk + kc * 2048);
            const float4* s2 = (const float4*)(tv + kc * 2048);
            float4* d1 = (float4*)tkc;
            float4* d2 = (float4*)tvc;
            d1[tid * 2]     = s1[tid * 2];
            d1[tid * 2 + 1] = s1[tid * 2 + 1];
            d2[tid * 2]     = s2[tid * 2];
            d2[tid * 2 + 1] = s2[tid * 2 + 1];
            if (last) {
                const float4* s3 = (const float4*)(tq + kc * 2048);
                float4* d3 = (float4*)tqc;
                d3[tid * 2]     = s3[tid * 2];
                d3[tid * 2 + 1] = s3[tid * 2 + 1];
            }
        }
        __syncthreads();
        for (int o = 0; o < 16; ++o) {
            int idx = o * 256 + tid;
            int b = idx >> 7, hh = idx & 127;
            const float* os = &out_s[b * 128 + kc * 16];
            #pragma unroll
            for (int k2 = 0; k2 < 16; ++k2) {
                float ov = os[k2];
                a_tr[o] += ov * tkc[k2 * 128 + hh];
                a_lb[o] += ov * tvc[k2 * 128 + hh];
                if (last) a_tq[o] += ov * tqc[k2 * 128 + hh];
            }
        }
    }
    for (int o = 0; o < 16; ++o) {
        int idx = o * 256 + tid;
        int b = idx >> 7, hh = idx & 127;  // value = trv[t][b][hh]
        _Float16 v16 = (_Float16)a_tr[o];
        int p = hh & 63;
        rwP[t * 4096 + ((p >> 3) << 9) + ((2 * b + (hh >> 6)) << 3) + (p & 7)] = v16;
        int q = ((hh & 1) << 5) + b;
        clP[t * 4096 + ((q >> 3) << 9) + ((hh >> 1) << 3) + (q & 7)] = v16;
        lblT[t * 4096 + hh * 32 + b] = a_lb[o];
        if (last) outq[idx] = a_tq[o];
    }
}

// ---------------- step building blocks ----------------
#define DPP_ADD(S, CTRL)                                                           \
  do { int _d = __builtin_amdgcn_update_dpp(0, __float_as_int(S), (CTRL), 0xF,     \
                                            0xF, true);                            \
       (S) += __int_as_float(_d); } while (0)

#if __has_builtin(__builtin_amdgcn_fdot2)
#define FDOT2(ci, gi, acc)                                                         \
  __builtin_amdgcn_fdot2(__builtin_bit_cast(h2, (ci)),                             \
                         __builtin_bit_cast(h2, (gi)), (acc), false)
#else
static __device__ __forceinline__ float fdot2_sw(int a, int b, float c) {
    h2 ha = __builtin_bit_cast(h2, a), hb2 = __builtin_bit_cast(h2, b);
    return fmaf((float)ha.y, (float)hb2.y, fmaf((float)ha.x, (float)hb2.x, c));
}
#define FDOT2(ci, gi, acc) fdot2_sw((ci), (gi), (acc))
#endif

// phase A: pred via fdot2 against fp16 w in LDS (8 b128 broadcast reads)
#define PHASE_A(HSEL, BMV, LBV, GOUT)                                              \
  do {                                                                             \
    float f0 = 0.f, f1 = 0.f, f2 = 0.f, f3 = 0.f;                                  \
    _Pragma("unroll")                                                              \
    for (int j = 0; j < 8; ++j) {                                                  \
      int4 xj = __builtin_bit_cast(int4, rw[j]);                                   \
      int4 wj = *(const int4*)&w16[HSEL][hf32i + 4 * j];                           \
      f0 = FDOT2(xj.x, wj.x, f0); f1 = FDOT2(xj.y, wj.y, f1);                      \
      f2 = FDOT2(xj.z, wj.z, f2); f3 = FDOT2(xj.w, wj.w, f3);                      \
    }                                                                              \
    float pp = (f0 + f2) + (f1 + f3);                                              \
    int po = __builtin_amdgcn_update_dpp(0, __float_as_int(pp), 0xB1, 0xF, 0xF,    \
                                         true);                                    \
    GOUT = (pp + __int_as_float(po)) + (BMV) - (LBV);  /* unscaled grad */         \
  } while (0)

#define PACK_G(GH, PKG)                                                            \
  do {                                                                             \
    int gnb = __builtin_amdgcn_update_dpp(0, __float_as_int(GH), 0x4E, 0xF, 0xF,   \
                                          true);                                   \
    PKG = __builtin_bit_cast(int,                                                  \
        __builtin_amdgcn_cvt_pkrtz(GH, __int_as_float(gnb)));                      \
  } while (0)

#define GSUM_EXACT(GH, OUT)                                                        \
  do {                                                                             \
    float _s = GH;                                                                 \
    DPP_ADD(_s, 0x4E); DPP_ADD(_s, 0x124); DPP_ADD(_s, 0x128);                     \
    _s += __shfl_xor(_s, 16); _s += __shfl_xor(_s, 32);                            \
    OUT = _s;                                                                      \
  } while (0)

#define PHASE_B(GP, GK0, GK1)                                                      \
  do {                                                                             \
    float f0 = 0.f, f1 = 0.f, f2 = 0.f, f3 = 0.f;                                  \
    float f4 = 0.f, f5 = 0.f, f6 = 0.f, f7 = 0.f;                                  \
    _Pragma("unroll")                                                              \
    for (int j = 0; j < 4; ++j) {                                                  \
      int4 cj = __builtin_bit_cast(int4, cl[j]);                                   \
      f0 = FDOT2(cj.x, GP[4 * j + 0], f0); f1 = FDOT2(cj.y, GP[4 * j + 1], f1);    \
      f2 = FDOT2(cj.z, GP[4 * j + 2], f2); f3 = FDOT2(cj.w, GP[4 * j + 3], f3);    \
    }                                                                              \
    _Pragma("unroll")                                                              \
    for (int j = 0; j < 4; ++j) {                                                  \
      int4 cj = __builtin_bit_cast(int4, cl[j + 4]);                               \
      f4 = FDOT2(cj.x, GP[4 * j + 0], f4); f5 = FDOT2(cj.y, GP[4 * j + 1], f5);    \
      f6 = FDOT2(cj.z, GP[4 * j + 2], f6); f7 = FDOT2(cj.w, GP[4 * j + 3], f7);    \
    }                                                                              \
    GK0 = cg * ((f0 + f2) + (f1 + f3));                                            \
    GK1 = cg * ((f4 + f6) + (f5 + f7));                                            \
  } while (0)

#define ADAM_W(GK, M, V, W)                                                        \
  do {                                                                             \
    M = fmaf(BB1, M, OB1 * (GK));                                                  \
    V = fmaf(BB2, V, OB2 * (GK) * (GK));                                           \
    W = fmaf(M * __builtin_amdgcn_rsqf(V + SEPS), na, W);                          \
  } while (0)

// ---------------- K3: Adam scan — 2 h per wave, shared tiles ----------------
// Tiles rw/cl are h-independent -> shared by both scans; the two independent
// dependency chains (A->g->readlane->B->Adam->LDS-w) interleave on the SIMD.
__global__
__attribute__((amdgpu_flat_work_group_size(64, 64), amdgpu_waves_per_eu(1, 1)))
void k_scan(
    const _Float16* __restrict__ rwP, const _Float16* __restrict__ clP,
    const float* __restrict__ lblT,
    const float* __restrict__ Wm0, const float* __restrict__ bm0,
    const float* __restrict__ outq, float* __restrict__ hi_ws) {
    const int h0 = 2 * blockIdx.x, h1 = h0 + 1;
    const int lane = threadIdx.x;
    const int row = lane >> 1;
    const int hf = lane & 1;
    const int hf32i = hf * 32;           // int-pair base into w16 row
    const int li0 = h0 * 32 + row;
    const int li1 = h1 * 32 + row;

    __shared__ __align__(16) int w16[2][64];     // fp16 w copies (pairs)
    __shared__ __align__(16) float ew[2][128];   // fp32 epilogue exchange

    // Adam state: lane owns Wm[h][2*lane], Wm[h][2*lane+1] for both h
    float2 wv0 = *(const float2*)&Wm0[h0 * 128 + 2 * lane];
    float2 wv1 = *(const float2*)&Wm0[h1 * 128 + 2 * lane];
    float w00 = wv0.x, w01 = wv0.y, w10 = wv1.x, w11 = wv1.y;
    float mW00 = 0.f, vW00 = 0.f, mW01 = 0.f, vW01 = 0.f;
    float mW10 = 0.f, vW10 = 0.f, mW11 = 0.f, vW11 = 0.f;
    float bm0v = bm0[h0], bm1v = bm0[h1];
    float mb0 = 0.f, vb0 = 0.f, mb1 = 0.f, vb1 = 0.f;
    float pb1 = 1.f, pb2 = 1.f;

    w16[0][lane] = __builtin_bit_cast(int, __builtin_amdgcn_cvt_pkrtz(w00, w01));
    w16[1][lane] = __builtin_bit_cast(int, __builtin_amdgcn_cvt_pkrtz(w10, w11));

    // shared tiles, depth-1
    h8 rw[8], cl[8];
    float lb0v, lb1v;
    {
        const h8* rs = (const h8*)(rwP);
        const h8* cs = (const h8*)(clP);
        #pragma unroll
        for (int j = 0; j < 8; ++j) rw[j] = rs[j * 64 + lane];
        #pragma unroll
        for (int j = 0; j < 8; ++j) cl[j] = cs[j * 64 + lane];
        lb0v = lblT[li0];
        lb1v = lblT[li1];
    }

    const float cg = 2.0f / 4096.0f;
    const float lr = 0.01f, BB1 = 0.9f, BB2 = 0.999f;
    const float OB1 = 0.1f, OB2 = 0.001f;
    const float SEPS = 1e-16f;

    for (int t = 0; t < T_; ++t) {
        pb1 *= BB1; pb2 *= BB2;
        const float na = (-lr) * __builtin_amdgcn_sqrtf(1.0f - pb2) *
                         __builtin_amdgcn_rcpf(1.0f - pb1);
        const int tpre = (t + 1 < T_) ? (t + 1) : (T_ - 1);

        float g0, g1;
        PHASE_A(0, bm0v, lb0v, g0);
        PHASE_A(1, bm1v, lb1v, g1);

        // prefetch shared rows + both lbls for t+1 (rw just consumed)
        {
            const h8* rs = (const h8*)(rwP + (size_t)tpre * 4096);
            #pragma unroll
            for (int j = 0; j < 8; ++j) rw[j] = rs[j * 64 + lane];
            lb0v = lblT[(size_t)tpre * 4096 + li0];
            lb1v = lblT[(size_t)tpre * 4096 + li1];
        }

        int pkg0, pkg1;
        PACK_G(g0, pkg0);
        PACK_G(g1, pkg1);
        float gs0, gs1;
        GSUM_EXACT(g0, gs0);
        GSUM_EXACT(g1, gs1);

        int gp0[16], gp1[16];
        #pragma unroll
        for (int i = 0; i < 16; ++i) {
            gp0[i] = __builtin_amdgcn_readlane(pkg0, 4 * i);
            gp1[i] = __builtin_amdgcn_readlane(pkg1, 4 * i);
        }

        float gk00, gk01, gk10, gk11;
        PHASE_B(gp0, gk00, gk01);
        PHASE_B(gp1, gk10, gk11);

        // prefetch shared cols for t+1 (cl just consumed)
        {
            const h8* cs = (const h8*)(clP + (size_t)tpre * 4096);
            #pragma unroll
            for (int j = 0; j < 8; ++j) cl[j] = cs[j * 64 + lane];
        }

        ADAM_W(gk00, mW00, vW00, w00);
        ADAM_W(gk01, mW01, vW01, w01);
        ADAM_W(gk10, mW10, vW10, w10);
        ADAM_W(gk11, mW11, vW11, w11);

        w16[0][lane] = __builtin_bit_cast(int, __builtin_amdgcn_cvt_pkrtz(w00, w01));
        w16[1][lane] = __builtin_bit_cast(int, __builtin_amdgcn_cvt_pkrtz(w10, w11));

        // bias Adam (redundant on all lanes; off the w critical chain)
        {
            float gb = cg * gs0;
            mb0 = fmaf(BB1, mb0, OB1 * gb);
            vb0 = fmaf(BB2, vb0, OB2 * gb * gb);
            bm0v = fmaf(mb0 * __builtin_amdgcn_rsqf(vb0 + SEPS), na, bm0v);
        }
        {
            float gb = cg * gs1;
            mb1 = fmaf(BB1, mb1, OB1 * gb);
            vb1 = fmaf(BB2, vb1, OB2 * gb * gb);
            bm1v = fmaf(mb1 * __builtin_amdgcn_rsqf(vb1 + SEPS), na, bm1v);
        }
    }

    // ---- epilogue: hi[:,h] = outq @ Wm_final[h,:] + bm_final (fp32 exact) ----
    *(float2*)&ew[0][2 * lane] = make_float2(w00, w01);
    *(float2*)&ew[1][2 * lane] = make_float2(w10, w11);

    const int rowbase = row * 128 + hf * 64;
    float4 eo[16];
    #pragma unroll
    for (int j = 0; j < 16; ++j) eo[j] = ((const float4*)(outq + rowbase))[j];
    {
        float a0 = 0.f, a1 = 0.f, a2 = 0.f, a3 = 0.f;
        #pragma unroll
        for (int j = 0; j < 16; ++j) {
            float4 wv4 = *(const float4*)&ew[0][hf * 64 + 4 * j];
            a0 = fmaf(eo[j].x, wv4.x, a0); a1 = fmaf(eo[j].y, wv4.y, a1);
            a2 = fmaf(eo[j].z, wv4.z, a2); a3 = fmaf(eo[j].w, wv4.w, a3);
        }
        float pp = (a0 + a2) + (a1 + a3);
        int po = __builtin_amdgcn_update_dpp(0, __float_as_int(pp), 0xB1, 0xF, 0xF, true);
        float pred = pp + __int_as_float(po);
        if (hf == 0) hi_ws[row * 128 + h0] = pred + bm0v;
    }
    {
        float a0 = 0.f, a1 = 0.f, a2 = 0.f, a3 = 0.f;
        #pragma unroll
        for (int j = 0; j < 16; ++j) {
            float4 wv4 = *(const float4*)&ew[1][hf * 64 + 4 * j];
            a0 = fmaf(eo[j].x, wv4.x, a0); a1 = fmaf(eo[j].y, wv4.y, a1);
            a2 = fmaf(eo[j].z, wv4.z, a2); a3 = fmaf(eo[j].w, wv4.w, a3);
        }
        float pp = (a0 + a2) + (a1 + a3);
        int po = __builtin_amdgcn_update_dpp(0, __float_as_int(pp), 0xB1, 0xF, 0xF, true);
        float pred = pp + __int_as_float(po);
        if (hf == 0) hi_ws[row * 128 + h1] = pred + bm1v;
    }
}

// ---------------- K4: y = hi@W_ho.T + b_o ; out = y@out_W.T + out_b ----------------
__global__ void k_out(const float* __restrict__ hi, const float* __restrict__ Who,
                      const float* __restrict__ bo, const float* __restrict__ outW,
                      const float* __restrict__ outb, float* __restrict__ dout) {
    int b = blockIdx.x, hh = threadIdx.x;
    __shared__ float hrow[128];
    __shared__ float part[2];
    hrow[hh] = hi[b * 128 + hh];
    __syncthreads();
    float acc = bo[hh];
    #pragma unroll 4
    for (int k = 0; k < 128; ++k) acc += hrow[k] * Who[hh * 128 + k];
    float v = acc * outW[hh];
    v += __shfl_down(v, 32, 64);
    v += __shfl_down(v, 16, 64);
    v += __shfl_down(v, 8, 64);
    v += __shfl_down(v, 4, 64);
    v += __shfl_down(v, 2, 64);
    v += __shfl_down(v, 1, 64);
    if ((hh & 63) == 0) part[hh >> 6] = v;
    __syncthreads();
    if (hh == 0) dout[b] = part[0] + part[1] + outb[0];
}

extern "C" void kernel_launch(void* const* d_in, const int* in_sizes, int n_in,
                              void* d_out, int out_size, void* d_ws, size_t ws_size,
                              hipStream_t stream) {
    (void)in_sizes; (void)n_in; (void)out_size; (void)ws_size;
    const float* in1   = (const float*)d_in[0];
    const float* in2   = (const float*)d_in[1];
    const float* in3   = (const float*)d_in[2];
    const float* h     = (const float*)d_in[3];
    const float* Wih   = (const float*)d_in[4];
    const float* Whh   = (const float*)d_in[5];
    const float* bh    = (const float*)d_in[6];
    const float* Who   = (const float*)d_in[7];
    const float* bo    = (const float*)d_in[8];
    const float* wl    = (const float*)d_in[9];
    const float* bl    = (const float*)d_in[10];
    const float* wsc   = (const float*)d_in[11];
    const float* bsc   = (const float*)d_in[12];
    const float* tk    = (const float*)d_in[13];
    const float* tv    = (const float*)d_in[14];
    const float* tq    = (const float*)d_in[15];
    const float* Wm0   = (const float*)d_in[16];
    const float* bm0   = (const float*)d_in[17];
    const float* outW  = (const float*)d_in[18];
    const float* outb  = (const float*)d_in[19];
    float* out = (float*)d_out;

    float* wsf = (float*)d_ws;
    float*    xf    = wsf;                               // 49152 f
    float*    hb    = wsf + 49152;                       // 4096 f
    _Float16* rwH   = (_Float16*)(wsf + 53248);          // 1048576 halfs
    _Float16* clH   = (_Float16*)(wsf + 53248 + 524288); // 1048576 halfs
    float*    lblT  = wsf + 53248 + 1048576;             // 1048576 f
    float*    outq  = wsf + 53248 + 2097152;             // 4096 f
    float*    hi_ws = wsf + 53248 + 2101248;             // 4096 f

    k_front<<<dim3(32, 7), 256, 0, stream>>>(in1, in2, wl, bl, wsc, bsc,
                                             h, Whh, bh, xf, hb, out);
    k_feat<<<256, 256, 0, stream>>>(xf, in3, hb, Wih, tk, tv, tq,
                                    rwH, clH, lblT, outq);
    k_scan<<<64, 64, 0, stream>>>(rwH, clH, lblT, Wm0, bm0, outq, hi_ws);
    k_out<<<32, 128, 0, stream>>>(hi_ws, Who, bo, outW, outb, out);
}

// Round 12
// 300.178 us; speedup vs baseline: 3.3229x; 1.1733x over previous
//
#include <hip/hip_runtime.h>
#include <math.h>

#define B_ 32
#define T_ 256
#define H_ 128
#define KL_ 500
#define KS_ 10

typedef _Float16 h8 __attribute__((ext_vector_type(8)));  // 16B = 8 fp16
typedef _Float16 h2 __attribute__((ext_vector_type(2)));

// ---------------- K1: convs (+ fused hb) ----------------
__global__ void k_front(const float* __restrict__ in1, const float* __restrict__ in2,
                        const float* __restrict__ wl, const float* __restrict__ bl,
                        const float* __restrict__ ws, const float* __restrict__ bs,
                        const float* __restrict__ h, const float* __restrict__ Whh,
                        const float* __restrict__ bh,
                        float* __restrict__ xf, float* __restrict__ hb,
                        float* __restrict__ dout) {
    int b = blockIdx.x, oc = blockIdx.y;
    int t = threadIdx.x;  // 256 threads
    if (oc == 6) {
        __shared__ float hrow[128];
        if (t < 128) hrow[t] = h[b * 128 + t];
        __syncthreads();
        if (t < 128) {
            float acc = bh[t];
            #pragma unroll 4
            for (int k = 0; k < 128; ++k) acc += hrow[k] * Whh[t * 128 + k];
            hb[b * 128 + t] = acc;
            dout[32 + b * 128 + t] = hrow[t];
        }
        return;
    }
    __shared__ float s_in[755 * 3];
    __shared__ float s_w[3 * KL_];
    if (oc < 3) {
        int o = oc;
        for (int i = t; i < 755 * 3; i += 256) s_in[i] = in1[b * 755 * 3 + i];
        for (int i = t; i < 3 * KL_; i += 256) s_w[i] = wl[o * 3 * KL_ + i];
        __syncthreads();
        float acc = bl[o];
        for (int i = 0; i < 3; ++i) {
            const float* wrow = &s_w[i * KL_];
            #pragma unroll 4
            for (int k = 0; k < KL_; ++k)
                acc += s_in[(t + k) * 3 + i] * wrow[k];
        }
        xf[(b * T_ + t) * 6 + o] = acc;
    } else {
        int o = oc - 3;
        for (int i = t; i < 265 * 3; i += 256) s_in[i] = in2[b * 265 * 3 + i];
        for (int i = t; i < 3 * KS_; i += 256) s_w[i] = ws[o * 3 * KS_ + i];
        __syncthreads();
        float acc = bs[o];
        for (int i = 0; i < 3; ++i) {
            #pragma unroll
            for (int k = 0; k < KS_; ++k)
                acc += s_in[(t + k) * 3 + i] * s_w[i * KS_ + k];
        }
        xf[(b * T_ + t) * 6 + 3 + o] = acc;
    }
}

// ---------------- K2: features -> lane-permuted fp16 tiles ----------------
__global__ void k_feat(const float* __restrict__ xf, const float* __restrict__ in3,
                       const float* __restrict__ hb, const float* __restrict__ Wih,
                       const float* __restrict__ tk, const float* __restrict__ tv,
                       const float* __restrict__ tq,
                       _Float16* __restrict__ rwP, _Float16* __restrict__ clP,
                       float* __restrict__ lblT, float* __restrict__ outq) {
    int t = blockIdx.x;
    int tid = threadIdx.x;
    __shared__ float out_s[B_ * H_];
    __shared__ __align__(16) float tkc[16 * H_];
    __shared__ __align__(16) float tvc[16 * H_];
    __shared__ __align__(16) float tqc[16 * H_];

    for (int o = 0; o < 16; ++o) {
        int idx = o * 256 + tid;
        int b = idx >> 7, hh = idx & 127;
        const float* w = &Wih[hh * 9];
        const float* x6 = &xf[(b * T_ + t) * 6];
        const float* x3 = &in3[(b * T_ + t) * 3];
        float acc = hb[idx];
        acc += x6[0] * w[0] + x6[1] * w[1] + x6[2] * w[2]
             + x6[3] * w[3] + x6[4] * w[4] + x6[5] * w[5]
             + x3[0] * w[6] + x3[1] * w[7] + x3[2] * w[8];
        out_s[idx] = acc;
    }
    __syncthreads();

    float a_tr[16], a_lb[16], a_tq[16];
    #pragma unroll
    for (int o = 0; o < 16; ++o) { a_tr[o] = 0.f; a_lb[o] = 0.f; a_tq[o] = 0.f; }
    const bool last = (t == T_ - 1);

    for (int kc = 0; kc < 8; ++kc) {
        __syncthreads();
        {
            const float4* s1 = (const float4*)(tk + kc * 2048);
            const float4* s2 = (const float4*)(tv + kc * 2048);
            float4* d1 = (float4*)tkc;
            float4* d2 = (float4*)tvc;
            d1[tid * 2]     = s1[tid * 2];
            d1[tid * 2 + 1] = s1[tid * 2 + 1];
            d2[tid * 2]     = s2[tid * 2];
            d2[tid * 2 + 1] = s2[tid * 2 + 1];
            if (last) {
                const float4* s3 = (const float4*)(tq + kc * 2048);
                float4* d3 = (float4*)tqc;
                d3[tid * 2]     = s3[tid * 2];
                d3[tid * 2 + 1] = s3[tid * 2 + 1];
            }
        }
        __syncthreads();
        for (int o = 0; o < 16; ++o) {
            int idx = o * 256 + tid;
            int b = idx >> 7, hh = idx & 127;
            const float* os = &out_s[b * 128 + kc * 16];
            #pragma unroll
            for (int k2 = 0; k2 < 16; ++k2) {
                float ov = os[k2];
                a_tr[o] += ov * tkc[k2 * 128 + hh];
                a_lb[o] += ov * tvc[k2 * 128 + hh];
                if (last) a_tq[o] += ov * tqc[k2 * 128 + hh];
            }
        }
    }
    for (int o = 0; o < 16; ++o) {
        int idx = o * 256 + tid;
        int b = idx >> 7, hh = idx & 127;  // value = trv[t][b][hh]
        _Float16 v16 = (_Float16)a_tr[o];
        int p = hh & 63;
        rwP[t * 4096 + ((p >> 3) << 9) + ((2 * b + (hh >> 6)) << 3) + (p & 7)] = v16;
        int q = ((hh & 1) << 5) + b;
        clP[t * 4096 + ((q >> 3) << 9) + ((hh >> 1) << 3) + (q & 7)] = v16;
        lblT[t * 4096 + hh * 32 + b] = a_lb[o];
        if (last) outq[idx] = a_tq[o];
    }
}

// ---------------- step building blocks ----------------
#define DPP_ADD(S, CTRL)                                                           \
  do { int _d = __builtin_amdgcn_update_dpp(0, __float_as_int(S), (CTRL), 0xF,     \
                                            0xF, true);                            \
       (S) += __int_as_float(_d); } while (0)

#if __has_builtin(__builtin_amdgcn_fdot2)
#define FDOT2(ci, gi, acc)                                                         \
  __builtin_amdgcn_fdot2(__builtin_bit_cast(h2, (ci)),                             \
                         __builtin_bit_cast(h2, (gi)), (acc), false)
#else
static __device__ __forceinline__ float fdot2_sw(int a, int b, float c) {
    h2 ha = __builtin_bit_cast(h2, a), hb2 = __builtin_bit_cast(h2, b);
    return fmaf((float)ha.y, (float)hb2.y, fmaf((float)ha.x, (float)hb2.x, c));
}
#define FDOT2(ci, gi, acc) fdot2_sw((ci), (gi), (acc))
#endif

// ---------------- K3: Adam scan — 1 h per wave, lean fdot2 step ----------------
__global__
__attribute__((amdgpu_flat_work_group_size(64, 64), amdgpu_waves_per_eu(1, 1)))
void k_scan(
    const _Float16* __restrict__ rwP, const _Float16* __restrict__ clP,
    const float* __restrict__ lblT,
    const float* __restrict__ Wm0, const float* __restrict__ bm0,
    const float* __restrict__ outq, float* __restrict__ hi_ws) {
    const int h = blockIdx.x;
    const int lane = threadIdx.x;
    const int row = lane >> 1;
    const int hf = lane & 1;
    const int hf32i = hf * 32;           // int-pair base into w16
    const int lblidx = h * 32 + row;

    __shared__ __align__(16) int w16[64];      // fp16 w copy (pairs)
    __shared__ __align__(16) float ew[128];    // fp32 epilogue exchange

    // Adam state: lane owns Wm[h][2*lane], Wm[h][2*lane+1]
    float2 wv = *(const float2*)&Wm0[h * 128 + 2 * lane];
    float w0 = wv.x, w1 = wv.y;
    float mW0 = 0.f, vW0 = 0.f, mW1 = 0.f, vW1 = 0.f;
    float bm = bm0[h];
    float mb = 0.f, vb = 0.f, pb1 = 1.f, pb2 = 1.f;

    w16[lane] = __builtin_bit_cast(int, __builtin_amdgcn_cvt_pkrtz(w0, w1));

    h8 rw[8], cl[8];
    float lbl;
    {
        const h8* rs = (const h8*)(rwP);
        const h8* cs = (const h8*)(clP);
        #pragma unroll
        for (int j = 0; j < 8; ++j) rw[j] = rs[j * 64 + lane];
        #pragma unroll
        for (int j = 0; j < 8; ++j) cl[j] = cs[j * 64 + lane];
        lbl = lblT[lblidx];
    }

    const float cg = 2.0f / 4096.0f;
    const float lr = 0.01f, BB1 = 0.9f, BB2 = 0.999f;
    const float OB1 = 0.1f, OB2 = 0.001f;
    const float SEPS = 1e-16f;

    for (int t = 0; t < T_; ++t) {
        pb1 *= BB1; pb2 *= BB2;
        const float na = (-lr) * __builtin_amdgcn_sqrtf(1.0f - pb2) *
                         __builtin_amdgcn_rcpf(1.0f - pb1);
        const int tpre = (t + 1 < T_) ? (t + 1) : (T_ - 1);

        // ---- phase A: pred via fdot2 against fp16 w in LDS ----
        float g;
        {
            float f0 = 0.f, f1 = 0.f, f2 = 0.f, f3 = 0.f;
            #pragma unroll
            for (int j = 0; j < 8; ++j) {
                int4 xj = __builtin_bit_cast(int4, rw[j]);
                int4 wj = *(const int4*)&w16[hf32i + 4 * j];
                f0 = FDOT2(xj.x, wj.x, f0); f1 = FDOT2(xj.y, wj.y, f1);
                f2 = FDOT2(xj.z, wj.z, f2); f3 = FDOT2(xj.w, wj.w, f3);
            }
            float pp = (f0 + f2) + (f1 + f3);
            int po = __builtin_amdgcn_update_dpp(0, __float_as_int(pp), 0xB1, 0xF, 0xF, true);
            g = (pp + __int_as_float(po)) + bm - lbl;   // unscaled grad
        }

        // prefetch rows + lbl for t+1 (rw just consumed)
        {
            const h8* rs = (const h8*)(rwP + (size_t)tpre * 4096);
            #pragma unroll
            for (int j = 0; j < 8; ++j) rw[j] = rs[j * 64 + lane];
            lbl = lblT[(size_t)tpre * 4096 + lblidx];
        }

        // pack (g[2i], g[2i+1]) on lanes 4i
        int pkg;
        {
            int gnb = __builtin_amdgcn_update_dpp(0, __float_as_int(g), 0x4E, 0xF, 0xF, true);
            pkg = __builtin_bit_cast(int,
                __builtin_amdgcn_cvt_pkrtz(g, __int_as_float(gnb)));
        }
        // bias grad: exact fp32 butterfly over the 32 distinct g's
        float gsum = g;
        DPP_ADD(gsum, 0x4E); DPP_ADD(gsum, 0x124); DPP_ADD(gsum, 0x128);
        gsum += __shfl_xor(gsum, 16); gsum += __shfl_xor(gsum, 32);

        // 16 packed readlanes
        int gp[16];
        #pragma unroll
        for (int i = 0; i < 16; ++i)
            gp[i] = __builtin_amdgcn_readlane(pkg, 4 * i);

        // ---- phase B: 32 dot2 for this lane's two columns ----
        float gk0, gk1;
        {
            float f0 = 0.f, f1 = 0.f, f2 = 0.f, f3 = 0.f;
            float f4 = 0.f, f5 = 0.f, f6 = 0.f, f7 = 0.f;
            #pragma unroll
            for (int j = 0; j < 4; ++j) {
                int4 cj = __builtin_bit_cast(int4, cl[j]);
                f0 = FDOT2(cj.x, gp[4 * j + 0], f0); f1 = FDOT2(cj.y, gp[4 * j + 1], f1);
                f2 = FDOT2(cj.z, gp[4 * j + 2], f2); f3 = FDOT2(cj.w, gp[4 * j + 3], f3);
            }
            #pragma unroll
            for (int j = 0; j < 4; ++j) {
                int4 cj = __builtin_bit_cast(int4, cl[j + 4]);
                f4 = FDOT2(cj.x, gp[4 * j + 0], f4); f5 = FDOT2(cj.y, gp[4 * j + 1], f5);
                f6 = FDOT2(cj.z, gp[4 * j + 2], f6); f7 = FDOT2(cj.w, gp[4 * j + 3], f7);
            }
            gk0 = cg * ((f0 + f2) + (f1 + f3));
            gk1 = cg * ((f4 + f6) + (f5 + f7));
        }

        // prefetch cols for t+1 (cl just consumed)
        {
            const h8* cs = (const h8*)(clP + (size_t)tpre * 4096);
            #pragma unroll
            for (int j = 0; j < 8; ++j) cl[j] = cs[j * 64 + lane];
        }

        // ---- Adam W ----
        mW0 = fmaf(BB1, mW0, OB1 * gk0);
        vW0 = fmaf(BB2, vW0, OB2 * gk0 * gk0);
        w0 = fmaf(mW0 * __builtin_amdgcn_rsqf(vW0 + SEPS), na, w0);
        mW1 = fmaf(BB1, mW1, OB1 * gk1);
        vW1 = fmaf(BB2, vW1, OB2 * gk1 * gk1);
        w1 = fmaf(mW1 * __builtin_amdgcn_rsqf(vW1 + SEPS), na, w1);

        w16[lane] = __builtin_bit_cast(int, __builtin_amdgcn_cvt_pkrtz(w0, w1));

        // bias Adam (redundant on all lanes; off the w critical chain)
        {
            float gb = cg * gsum;
            mb = fmaf(BB1, mb, OB1 * gb);
            vb = fmaf(BB2, vb, OB2 * gb * gb);
            bm = fmaf(mb * __builtin_amdgcn_rsqf(vb + SEPS), na, bm);
        }
    }

    // ---- epilogue: hi[:,h] = outq @ Wm_final[h,:] + bm_final (fp32 exact) ----
    *(float2*)&ew[2 * lane] = make_float2(w0, w1);
    {
        const int rowbase = row * 128 + hf * 64;
        float a0 = 0.f, a1 = 0.f, a2 = 0.f, a3 = 0.f;
        #pragma unroll
        for (int j = 0; j < 16; ++j) {
            float4 xv = ((const float4*)(outq + rowbase))[j];
            float4 wv4 = *(const float4*)&ew[hf * 64 + 4 * j];
            a0 = fmaf(xv.x, wv4.x, a0); a1 = fmaf(xv.y, wv4.y, a1);
            a2 = fmaf(xv.z, wv4.z, a2); a3 = fmaf(xv.w, wv4.w, a3);
        }
        float pp = (a0 + a2) + (a1 + a3);
        int po = __builtin_amdgcn_update_dpp(0, __float_as_int(pp), 0xB1, 0xF, 0xF, true);
        float pred = pp + __int_as_float(po);
        if (hf == 0) hi_ws[row * 128 + h] = pred + bm;
    }
}

// ---------------- K4: y = hi@W_ho.T + b_o ; out = y@out_W.T + out_b ----------------
__global__ void k_out(const float* __restrict__ hi, const float* __restrict__ Who,
                      const float* __restrict__ bo, const float* __restrict__ outW,
                      const float* __restrict__ outb, float* __restrict__ dout) {
    int b = blockIdx.x, hh = threadIdx.x;
    __shared__ float hrow[128];
    __shared__ float part[2];
    hrow[hh] = hi[b * 128 + hh];
    __syncthreads();
    float acc = bo[hh];
    #pragma unroll 4
    for (int k = 0; k < 128; ++k) acc += hrow[k] * Who[hh * 128 + k];
    float v = acc * outW[hh];
    v += __shfl_down(v, 32, 64);
    v += __shfl_down(v, 16, 64);
    v += __shfl_down(v, 8, 64);
    v += __shfl_down(v, 4, 64);
    v += __shfl_down(v, 2, 64);
    v += __shfl_down(v, 1, 64);
    if ((hh & 63) == 0) part[hh >> 6] = v;
    __syncthreads();
    if (hh == 0) dout[b] = part[0] + part[1] + outb[0];
}

extern "C" void kernel_launch(void* const* d_in, const int* in_sizes, int n_in,
                              void* d_out, int out_size, void* d_ws, size_t ws_size,
                              hipStream_t stream) {
    (void)in_sizes; (void)n_in; (void)out_size; (void)ws_size;
    const float* in1   = (const float*)d_in[0];
    const float* in2   = (const float*)d_in[1];
    const float* in3   = (const float*)d_in[2];
    const float* h     = (const float*)d_in[3];
    const float* Wih   = (const float*)d_in[4];
    const float* Whh   = (const float*)d_in[5];
    const float* bh    = (const float*)d_in[6];
    const float* Who   = (const float*)d_in[7];
    const float* bo    = (const float*)d_in[8];
    const float* wl    = (const float*)d_in[9];
    const float* bl    = (const float*)d_in[10];
    const float* wsc   = (const float*)d_in[11];
    const float* bsc   = (const float*)d_in[12];
    const float* tk    = (const float*)d_in[13];
    const float* tv    = (const float*)d_in[14];
    const float* tq    = (const float*)d_in[15];
    const float* Wm0   = (const float*)d_in[16];
    const float* bm0   = (const float*)d_in[17];
    const float* outW  = (const float*)d_in[18];
    const float* outb  = (const float*)d_in[19];
    float* out = (float*)d_out;

    float* wsf = (float*)d_ws;
    float*    xf    = wsf;                               // 49152 f
    float*    hb    = wsf + 49152;                       // 4096 f
    _Float16* rwH   = (_Float16*)(wsf + 53248);          // 1048576 halfs
    _Float16* clH   = (_Float16*)(wsf + 53248 + 524288); // 1048576 halfs
    float*    lblT  = wsf + 53248 + 1048576;             // 1048576 f
    float*    outq  = wsf + 53248 + 2097152;             // 4096 f
    float*    hi_ws = wsf + 53248 + 2101248;             // 4096 f

    k_front<<<dim3(32, 7), 256, 0, stream>>>(in1, in2, wl, bl, wsc, bsc,
                                             h, Whh, bh, xf, hb, out);
    k_feat<<<256, 256, 0, stream>>>(xf, in3, hb, Wih, tk, tv, tq,
                                    rwH, clH, lblT, outq);
    k_scan<<<128, 64, 0, stream>>>(rwH, clH, lblT, Wm0, bm0, outq, hi_ws);
    k_out<<<32, 128, 0, stream>>>(hi_ws, Who, bo, outW, outb, out);
}